// Round 7
// baseline (212.641 us; speedup 1.0000x reference)
//
#include <hip/hip_runtime.h>

#define N_NODES 50000
#define N_EDGES 800000
#define F1 64
#define F2 16
#define NBINS 196      // ceil(50000/256)
#define BIN_SHIFT 8    // 256 nodes per bin
#define EPB 4096       // edges per binscatter block
#define NSB ((N_EDGES + EPB - 1) / EPB)   // 196
#define SCAN_NB 196
#define STAGE_MAX 6144 // max edges/bin (mean 4082, sigma 64)
#define GEMM1_NB (N_NODES / 4)  // 12500

// ---------------- degree count ----------------
__global__ void k_count(const int* __restrict__ dst, int* __restrict__ cnt) {
    int i = blockIdx.x * blockDim.x + threadIdx.x;
    if (i < N_EDGES) atomicAdd(&cnt[dst[i]], 1);
}

// ---------------- scan step 1 (+dinv fused) ----------------
__global__ void k_scan_local(const int* __restrict__ cnt, float* __restrict__ dinv,
                             int* __restrict__ node_start, int* __restrict__ bsum) {
    __shared__ int tmp[256];
    int t = threadIdx.x;
    int g = blockIdx.x * 256 + t;
    int v = (g < N_NODES) ? cnt[g] : 0;
    if (g < N_NODES) dinv[g] = rsqrtf(1.0f + (float)v);  // +1 self-loop
    tmp[t] = v;
    __syncthreads();
    for (int s = 1; s < 256; s <<= 1) {
        int u = (t >= s) ? tmp[t - s] : 0;
        __syncthreads();
        tmp[t] += u;
        __syncthreads();
    }
    if (g < N_NODES) node_start[g] = tmp[t] - v;  // exclusive
    if (t == 255) bsum[blockIdx.x] = tmp[255];
}

// ---------------- scan step 2: each block redundantly scans bsum, adds prefix ----------------
__global__ void k_scan_add(int* __restrict__ node_start, const int* __restrict__ bsum,
                           int* __restrict__ cursor) {
    __shared__ int tmp[256];
    int t = threadIdx.x;
    tmp[t] = (t < SCAN_NB) ? bsum[t] : 0;
    __syncthreads();
    for (int s = 1; s < 256; s <<= 1) {
        int u = (t >= s) ? tmp[t - s] : 0;
        __syncthreads();
        tmp[t] += u;
        __syncthreads();
    }
    int add = (blockIdx.x == 0) ? 0 : tmp[blockIdx.x - 1];  // exclusive prefix for this block
    int g = blockIdx.x * 256 + t;
    if (g < N_NODES) {
        int v = node_start[g] + add;
        node_start[g] = v;
        if ((g & 255) == 0) cursor[g >> BIN_SHIFT] = v;  // bin base = node_start[b<<8]
    }
    if (g == 0) node_start[N_NODES] = N_EDGES;
}

// ---------------- fused: binscatter (blocks 0..NSB-1) || gemm1 h0'=dinv*(x@W1) ----------------
__global__ void __launch_bounds__(256) k_bs_gemm1(
        const int* __restrict__ src, const int* __restrict__ dst,
        int* __restrict__ cursor, unsigned* __restrict__ pairs,
        const float* __restrict__ x, const float* __restrict__ W1,
        const float* __restrict__ dinv, float* __restrict__ h0) {
    __shared__ int smem[5136];   // 20.5 KB, shared by both branches
    int t = threadIdx.x;         // 256

    if (blockIdx.x < NSB) {
        // ---- binscatter: coarse-bin edges by dst>>8 with coalesced flushes ----
        int* hist    = smem;            // 196
        int* loff    = smem + 196;
        int* lcur    = smem + 392;
        int* gbase   = smem + 588;
        int* scanbuf = smem + 784;      // 256
        unsigned* stage = (unsigned*)(smem + 1040);  // 4096
        int e0 = blockIdx.x * EPB;
        int eend = min(e0 + EPB, N_EDGES);

        for (int i = t; i < NBINS; i += 256) hist[i] = 0;
        __syncthreads();
        for (int e = e0 + t; e < eend; e += 256)
            atomicAdd(&hist[dst[e] >> BIN_SHIFT], 1);
        __syncthreads();
        int v = (t < NBINS) ? hist[t] : 0;
        scanbuf[t] = v;
        __syncthreads();
        for (int s = 1; s < 256; s <<= 1) {
            int u = (t >= s) ? scanbuf[t - s] : 0;
            __syncthreads();
            scanbuf[t] += u;
            __syncthreads();
        }
        if (t < NBINS) { loff[t] = scanbuf[t] - v; lcur[t] = scanbuf[t] - v; }
        __syncthreads();
        for (int e = e0 + t; e < eend; e += 256) {
            int d = dst[e];
            int b = d >> BIN_SHIFT;
            int pos = atomicAdd(&lcur[b], 1);
            stage[pos] = (unsigned)src[e] | ((unsigned)(d & 255) << 16);  // src < 2^16
        }
        __syncthreads();
        if (t < NBINS) gbase[t] = atomicAdd(&cursor[t], hist[t]);
        __syncthreads();
        int lane = t & 63, wid = t >> 6;
        for (int b = wid; b < NBINS; b += 4) {
            int n = hist[b], lb = loff[b], gb = gbase[b];
            for (int i = lane; i < n; i += 64) pairs[gb + i] = stage[lb + i];
        }
    } else {
        // ---- gemm1: h0' = dinv * (x @ W1), one wave per row ----
        float* Ws = (float*)smem;         // 4096
        float* Xs = (float*)smem + 4096;  // 256
        int bid = blockIdx.x - NSB;
        int row_local = t >> 6;
        int col = t & 63;
        int row = bid * 4 + row_local;

        for (int i = t; i < F1 * F1; i += 256) Ws[i] = W1[i];
        Xs[t] = x[bid * 4 * F1 + t];
        __syncthreads();

        const float* xr = &Xs[row_local * F1];
        float acc = 0.f;
#pragma unroll
        for (int k = 0; k < F1; ++k) acc += xr[k] * Ws[k * F1 + col];
        h0[row * F1 + col] = dinv[row] * acc;   // pre-scaled: kills per-edge dinv loads
    }
}

// ---------------- per-bin counting sort -> node-sorted ushort CSR ----------------
__global__ void k_binsort(const int* __restrict__ node_start, const unsigned* __restrict__ pairs,
                          unsigned short* __restrict__ csr) {
    __shared__ int hist[256];
    __shared__ int lcur[256];
    __shared__ int scanbuf[256];
    __shared__ unsigned short stage[STAGE_MAX];
    int t = threadIdx.x;                         // 256
    int b = blockIdx.x;
    int lo = b << BIN_SHIFT;
    int hi = min(lo + 256, N_NODES);
    int start = node_start[lo], end = node_start[hi];
    int n = end - start;

    hist[t] = 0;
    __syncthreads();
    for (int i = t; i < n; i += 256)
        atomicAdd(&hist[pairs[start + i] >> 16], 1);
    __syncthreads();
    int v = hist[t];
    scanbuf[t] = v;
    __syncthreads();
    for (int s = 1; s < 256; s <<= 1) {
        int u = (t >= s) ? scanbuf[t - s] : 0;
        __syncthreads();
        scanbuf[t] += u;
        __syncthreads();
    }
    lcur[t] = scanbuf[t] - v;
    __syncthreads();
    for (int i = t; i < n; i += 256) {
        unsigned p = pairs[start + i];
        int pos = atomicAdd(&lcur[p >> 16], 1);
        stage[pos] = (unsigned short)(p & 0xFFFF);
    }
    __syncthreads();
    for (int i = t; i < n; i += 256) csr[start + i] = stage[i];  // coalesced
}

// ---------------- fused layer-1 gather + layer-2 GEMM ----------------
// h0' rows are pre-scaled by dinv[src].  agg = dd*(sum h0'[s] + h0'[d]).
// h1'[d] = dinv[d] * ( relu(agg + b1) @ W2 )   (pre-scaled for gather2)
__global__ void __launch_bounds__(256) k_gather1f(
        const int* __restrict__ node_start, const unsigned short* __restrict__ csr,
        const float* __restrict__ dinv, const float4* __restrict__ h04,
        const float* __restrict__ b1, const float* __restrict__ W2,
        float* __restrict__ h1) {
    __shared__ float W2s[F1 * 17];     // stride 17: breaks 4-way bank conflict
    __shared__ float b1s[F1];
    __shared__ float4 rowbuf[4][16];   // per-wave staged row
    int t = threadIdx.x;               // 256 = 4 waves, one node per wave
    for (int i = t; i < F1 * F2; i += 256) W2s[(i >> 4) * 17 + (i & 15)] = W2[i];
    if (t < F1) b1s[t] = b1[t];
    __syncthreads();

    int lane = t & 63, wid = t >> 6;
    int j = lane >> 4, f = lane & 15;  // 4 edge-groups x float4 slice
    int d = blockIdx.x * 4 + wid;
    int start = node_start[d], end = node_start[d + 1];
    float4 acc = {0.f, 0.f, 0.f, 0.f};
    int i = start + j;
    for (; i + 4 < end; i += 8) {      // 2 chains for MLP
        int s0 = csr[i], s1 = csr[i + 4];
        float4 v0 = h04[s0 * 16 + f], v1 = h04[s1 * 16 + f];
        acc.x += v0.x + v1.x;
        acc.y += v0.y + v1.y;
        acc.z += v0.z + v1.z;
        acc.w += v0.w + v1.w;
    }
    if (i < end) {
        int s = csr[i];
        float4 v = h04[s * 16 + f];
        acc.x += v.x; acc.y += v.y; acc.z += v.z; acc.w += v.w;
    }
#pragma unroll
    for (int m = 16; m <= 32; m <<= 1) {
        acc.x += __shfl_xor(acc.x, m);
        acc.y += __shfl_xor(acc.y, m);
        acc.z += __shfl_xor(acc.z, m);
        acc.w += __shfl_xor(acc.w, m);
    }
    if (j == 0) {                      // agg + bias + relu, staged for the 64->16 matmul
        float dd = dinv[d];
        float4 sv = h04[d * 16 + f];   // = dd*h0[d] slice (pre-scaled)
        float4 r;
        r.x = fmaxf(dd * (acc.x + sv.x) + b1s[4 * f + 0], 0.f);
        r.y = fmaxf(dd * (acc.y + sv.y) + b1s[4 * f + 1], 0.f);
        r.z = fmaxf(dd * (acc.z + sv.z) + b1s[4 * f + 2], 0.f);
        r.w = fmaxf(dd * (acc.w + sv.w) + b1s[4 * f + 3], 0.f);
        rowbuf[wid][f] = r;
    }
    __syncthreads();                   // LDS visibility (straight-line, all threads reach)

    // matmul 64 -> 16: group g covers k in [16g,16g+16), lane c = output col
    int g = j, c = f;
    const float* row = (const float*)rowbuf[wid];
    float p = 0.f;
#pragma unroll
    for (int kk = 0; kk < 16; ++kk)
        p += row[g * 16 + kk] * W2s[(g * 16 + kk) * 17 + c];
    p += __shfl_xor(p, 16);
    p += __shfl_xor(p, 32);
    if (g == 0) h1[d * F2 + c] = dinv[d] * p;   // pre-scaled for gather2
}

// ---------------- layer 2 pull gather: out = b2 + dd*(sum h1'[s] + h1'[d]) ----------------
__global__ void k_gather2(const int* __restrict__ node_start, const unsigned short* __restrict__ csr,
                          const float* __restrict__ dinv, const float4* __restrict__ h14,
                          const float4* __restrict__ b24, float4* __restrict__ out4) {
    int t = threadIdx.x;                 // 256 = 4 waves, one node per wave
    int lane = t & 63;
    int j = lane >> 2, f = lane & 3;     // 16 edge-groups x 16B slice (F2=16)
    int d = blockIdx.x * 4 + (t >> 6);
    int start = node_start[d], end = node_start[d + 1];
    float4 acc = {0.f, 0.f, 0.f, 0.f};
    for (int i = start + j; i < end; i += 16) {
        int s = csr[i];
        float4 v = h14[s * 4 + f];       // pre-scaled row: no dinv load
        acc.x += v.x; acc.y += v.y; acc.z += v.z; acc.w += v.w;
    }
#pragma unroll
    for (int m = 4; m <= 32; m <<= 1) {
        acc.x += __shfl_xor(acc.x, m);
        acc.y += __shfl_xor(acc.y, m);
        acc.z += __shfl_xor(acc.z, m);
        acc.w += __shfl_xor(acc.w, m);
    }
    if (j == 0) {
        float dd = dinv[d];
        float4 sv = h14[d * 4 + f];
        float4 bb = b24[f];
        float4 r;
        r.x = bb.x + dd * (acc.x + sv.x);
        r.y = bb.y + dd * (acc.y + sv.y);
        r.z = bb.z + dd * (acc.z + sv.z);
        r.w = bb.w + dd * (acc.w + sv.w);
        out4[d * 4 + f] = r;
    }
}

extern "C" void kernel_launch(void* const* d_in, const int* in_sizes, int n_in,
                              void* d_out, int out_size, void* d_ws, size_t ws_size,
                              hipStream_t stream) {
    const float* x  = (const float*)d_in[0];          // [50000, 64]
    const int*   ei = (const int*)d_in[1];            // [2, 800000]
    const float* W1 = (const float*)d_in[2];          // [64, 64]
    const float* b1 = (const float*)d_in[3];          // [64]
    const float* W2 = (const float*)d_in[4];          // [64, 16]
    const float* b2 = (const float*)d_in[5];          // [16]
    float* out = (float*)d_out;                       // [50000, 16]

    const int* src = ei;
    const int* dst = ei + N_EDGES;

    // ws layout (4B words), no aliasing, 21.4 MB total:
    float*          dinv       = (float*)d_ws;                         // [0, 50048)
    int*            node_start = (int*)d_ws + 50048;                   // 50001 used
    int*            cursor     = (int*)d_ws + 100352;                  // 196
    int*            bsum       = (int*)d_ws + 100608;                  // 196
    unsigned short* csr        = (unsigned short*)((int*)d_ws + 100864);  // 800000 u16
    unsigned*       pairs      = (unsigned*)d_ws + 500864;             // 800000
    float*          h0         = (float*)d_ws + 1300864;               // 3,200,000 (pre-scaled)
    float*          h1         = (float*)d_ws + 4500864;               // 800,000 (pre-scaled)
    int*            nodecnt    = (int*)d_ws + 5300864;                 // 50048

    hipMemsetAsync(nodecnt, 0, N_NODES * sizeof(int), stream);
    k_count     <<<(N_EDGES + 255) / 256, 256, 0, stream>>>(dst, nodecnt);
    k_scan_local<<<SCAN_NB, 256, 0, stream>>>(nodecnt, dinv, node_start, bsum);
    k_scan_add  <<<SCAN_NB, 256, 0, stream>>>(node_start, bsum, cursor);
    k_bs_gemm1  <<<NSB + GEMM1_NB, 256, 0, stream>>>(src, dst, cursor, pairs, x, W1, dinv, h0);
    k_binsort   <<<NBINS, 256, 0, stream>>>(node_start, pairs, csr);
    k_gather1f  <<<N_NODES / 4, 256, 0, stream>>>(node_start, csr, dinv, (const float4*)h0,
                                                  b1, W2, h1);
    k_gather2   <<<N_NODES / 4, 256, 0, stream>>>(node_start, csr, dinv, (const float4*)h1,
                                                  (const float4*)b2, (float4*)out);
}